// Round 12
// baseline (140.896 us; speedup 1.0000x reference)
//
#include <hip/hip_runtime.h>

typedef __attribute__((ext_vector_type(8))) short short8;
typedef __attribute__((ext_vector_type(4))) short s4v;
typedef __attribute__((ext_vector_type(4))) float floatx4;
typedef __attribute__((ext_vector_type(4))) float f32x4;

#define BS 32768

__device__ __forceinline__ unsigned short f2bf(float f) {
  unsigned int u = __float_as_uint(f);
  u += 0x7fffu + ((u >> 16) & 1u);   // round-to-nearest-even
  return (unsigned short)(u >> 16);
}

// Transpose We [8][512][256] f32 -> WeT [8][256][512] bf16 (k-contiguous rows)
__global__ void prep_weT(const float* __restrict__ We, unsigned short* __restrict__ WeT) {
  int e  = blockIdx.x >> 6;
  int kc = blockIdx.x & 63;
  int h  = threadIdx.x;
  short8 pk;
#pragma unroll
  for (int j = 0; j < 8; ++j)
    pk[j] = (short)f2bf(We[e * 131072 + (kc * 8 + j) * 256 + h]);
  *reinterpret_cast<short8*>(&WeT[e * 131072 + h * 512 + kc * 8]) = pk;
}

// Wg [2][512][8] f32 -> WgT [16][512] bf16, row = t*8+e
__global__ void prep_wgT(const float* __restrict__ Wg, unsigned short* __restrict__ WgT) {
  int row = blockIdx.x;
  int t = row >> 3, e = row & 7;
  int lane = threadIdx.x;
  short8 pk;
#pragma unroll
  for (int j = 0; j < 8; ++j)
    pk[j] = (short)f2bf(Wg[t * 4096 + (lane * 8 + j) * 8 + e]);
  *reinterpret_cast<short8*>(&WgT[row * 512 + lane * 8]) = pk;
}

#define GLOAD16(SRC, DST) \
  __builtin_amdgcn_global_load_lds( \
      (const __attribute__((address_space(1))) unsigned int*)(SRC), \
      (__attribute__((address_space(3))) unsigned int*)(DST), 16, 0, 0)

// v12: 512 blocks x 512 thr (8 waves 2m x 4n, wave tile 32x64). Block = 64 rows
// x 256 cols x 8 experts x full K, fully fused (gates + epilogue + sigmoid).
// A in LDS dbuf (not regs) -> acc only 32 AGPR -> regs <= 128 -> 4 waves/SIMD
// with 2 independent blocks/CU (LDS ~56KB). BK=32. A bf16 parked in private
// global scratch (written during the gates sweep), restaged per expert.
__global__ __launch_bounds__(512, 4) void mmoe_main(
    const float* __restrict__ xv,            // [32768,512] f32
    const unsigned short* __restrict__ WeT,  // [8][256][512] bf16
    const unsigned short* __restrict__ WgT,  // [16][512] bf16
    const float* __restrict__ be,            // [8][256]
    const float* __restrict__ bg,            // [2][8]
    const float* __restrict__ Wt,            // [2][256]
    const float* __restrict__ bt,            // [2]
    unsigned short* __restrict__ Asc,        // [512 blocks][32768] bf16 scratch
    float* __restrict__ out)                 // [2][32768]
{
  __shared__ __attribute__((aligned(16))) unsigned char Abuf[2][4096];   // [64r][64B] swz
  __shared__ __attribute__((aligned(16))) unsigned char Bbuf[2][16384];  // [256c][64B] swz
  __shared__ float gates_lds[64][17];
  __shared__ float be_lds[2048];             // [8][256]
  __shared__ float red_lds[8][32][2];

  const int tid   = threadIdx.x;
  const int wave  = tid >> 6;
  const int lane  = tid & 63;
  const int row16 = lane & 15;
  const int kgrp  = lane >> 4;
  const int wm    = wave >> 2;   // 0..1
  const int wn    = wave & 3;    // 0..3
  const int b0    = blockIdx.x * 64;

  // frag k-offset within a 64B row (shared by A and B reads)
  const unsigned koff = ((unsigned)(kgrp * 16)) ^ ((unsigned)((row16 & 3) << 4));

  // ---- sweep: 16 kt of 32k — cvt xv->bf16 (LDS + private scratch), gates MFMA ----
  const int ar = tid >> 3, aq = tid & 7;                 // 8 thr/row, 4 floats each
  const unsigned ya = ((unsigned)(aq * 8)) ^ ((unsigned)((ar & 3) << 4));
  unsigned short* ascb = Asc + (size_t)blockIdx.x * 32768;

  floatx4 gacc = {0.f, 0.f, 0.f, 0.f};
  for (int kt = 0; kt < 16; ++kt) {
    f32x4 v = *reinterpret_cast<const f32x4*>(xv + (size_t)(b0 + ar) * 512 + kt * 32 + aq * 4);
    s4v pk;
    pk[0] = (short)f2bf(v[0]); pk[1] = (short)f2bf(v[1]);
    pk[2] = (short)f2bf(v[2]); pk[3] = (short)f2bf(v[3]);
    *reinterpret_cast<s4v*>(&Abuf[0][ar * 64 + ya]) = pk;
    *reinterpret_cast<s4v*>(&ascb[kt * 2048 + ar * 32 + (ya >> 1)]) = pk;
    __syncthreads();
    if (wave < 4) {   // gates: wave = m-frag
      short8 af = *reinterpret_cast<const short8*>(
          &Abuf[0][(wave * 16 + row16) * 64 + koff]);
      short8 wgf = *reinterpret_cast<const short8*>(&WgT[row16 * 512 + kt * 32 + kgrp * 8]);
      gacc = __builtin_amdgcn_mfma_f32_16x16x32_bf16(af, wgf, gacc, 0, 0, 0);
    }
    __syncthreads();
  }

  // softmax over experts (col=row16=t*8+e), per t-half of 8 lanes
  if (wave < 4) {
    float bgv = bg[row16];
#pragma unroll
    for (int j = 0; j < 4; ++j) {
      float v = gacc[j] + bgv;
      float mx = v;
      mx = fmaxf(mx, __shfl_xor(mx, 1));
      mx = fmaxf(mx, __shfl_xor(mx, 2));
      mx = fmaxf(mx, __shfl_xor(mx, 4));
      float p = __expf(v - mx);
      float s = p;
      s += __shfl_xor(s, 1);
      s += __shfl_xor(s, 2);
      s += __shfl_xor(s, 4);
      gates_lds[wave * 16 + kgrp * 4 + j][row16] = p / s;
    }
  }

  // be -> LDS; tower weights -> regs
#pragma unroll
  for (int j = 0; j < 4; ++j)
    be_lds[j * 512 + tid] = be[j * 512 + tid];
  float wtv[2][4];
#pragma unroll
  for (int t = 0; t < 2; ++t)
#pragma unroll
    for (int n = 0; n < 4; ++n)
      wtv[t][n] = Wt[t * 256 + wn * 64 + n * 16 + row16];

  asm volatile("s_waitcnt vmcnt(0)" ::: "memory");  // Ascratch stores visible
  __syncthreads();

  // ---- prologue: stage (e=0, kt=0) ----
  unsigned soffB[2];
#pragma unroll
  for (int i = 0; i < 2; ++i) {
    unsigned x = (unsigned)(i * 8192 + tid * 16);
    unsigned r2 = x >> 6;
    unsigned y2 = (x & 63u) ^ ((r2 & 3u) << 4);
    soffB[i] = r2 * 512u + (y2 >> 1);
  }
  if (wave < 4) GLOAD16(ascb + tid * 8, &Abuf[0][tid * 16]);
  GLOAD16(WeT + soffB[0], &Bbuf[0][(0 * 8 + wave) * 1024]);
  GLOAD16(WeT + soffB[1], &Bbuf[0][(1 * 8 + wave) * 1024]);

  // ---- main: 8 e x 16 kt(32); counted vmcnt; 2 barriers/phase ----
  float outacc[2][4][2];
#pragma unroll
  for (int m = 0; m < 2; ++m)
#pragma unroll
    for (int j = 0; j < 4; ++j) { outacc[m][j][0] = 0.f; outacc[m][j][1] = 0.f; }

  for (int e = 0; e < 8; ++e) {
    floatx4 acc[2][4];
#pragma unroll
    for (int m = 0; m < 2; ++m)
#pragma unroll
      for (int n = 0; n < 4; ++n) acc[m][n] = (floatx4){0.f, 0.f, 0.f, 0.f};

#pragma unroll
    for (int kt = 0; kt < 16; ++kt) {
      const int cur = kt & 1, nxt = cur ^ 1;     // parity compile-time (16 even)
      if (!((e == 7) && (kt == 15))) {
        const int ne  = (kt < 15) ? e : e + 1;
        const int nkt = (kt + 1) & 15;
        if (wave < 4) GLOAD16(ascb + nkt * 2048 + tid * 8, &Abuf[nxt][tid * 16]);
        const unsigned short* bbase = WeT + ne * 131072 + nkt * 32;
        GLOAD16(bbase + soffB[0], &Bbuf[nxt][(0 * 8 + wave) * 1024]);
        GLOAD16(bbase + soffB[1], &Bbuf[nxt][(1 * 8 + wave) * 1024]);
        if (wave < 4) asm volatile("s_waitcnt vmcnt(3)" ::: "memory");
        else          asm volatile("s_waitcnt vmcnt(2)" ::: "memory");
      } else {
        asm volatile("s_waitcnt vmcnt(0)" ::: "memory");
      }
      __builtin_amdgcn_s_barrier();              // stage(kt) landed for all waves
      __builtin_amdgcn_sched_barrier(0);

      short8 af0 = *reinterpret_cast<const short8*>(
          &Abuf[cur][(wm * 32 + row16) * 64 + koff]);
      short8 af1 = *reinterpret_cast<const short8*>(
          &Abuf[cur][(wm * 32 + 16 + row16) * 64 + koff]);
      short8 bf[4];
#pragma unroll
      for (int n = 0; n < 4; ++n)
        bf[n] = *reinterpret_cast<const short8*>(
            &Bbuf[cur][(wn * 64 + n * 16 + row16) * 64 + koff]);
      asm volatile("s_waitcnt lgkmcnt(0)" ::: "memory");
      __builtin_amdgcn_sched_barrier(0);
      __builtin_amdgcn_s_setprio(1);
#pragma unroll
      for (int n = 0; n < 4; ++n)
        acc[0][n] = __builtin_amdgcn_mfma_f32_16x16x32_bf16(af0, bf[n], acc[0][n], 0, 0, 0);
#pragma unroll
      for (int n = 0; n < 4; ++n)
        acc[1][n] = __builtin_amdgcn_mfma_f32_16x16x32_bf16(af1, bf[n], acc[1][n], 0, 0, 0);
      __builtin_amdgcn_s_setprio(0);
      __builtin_amdgcn_s_barrier();              // reads of buf(cur) done
      __builtin_amdgcn_sched_barrier(0);
    }

    // ---- expert epilogue (LDS/VALU only; next stage already in flight) ----
    float bev[4];
#pragma unroll
    for (int n = 0; n < 4; ++n)
      bev[n] = be_lds[e * 256 + wn * 64 + n * 16 + row16];
#pragma unroll
    for (int m2 = 0; m2 < 2; ++m2) {
#pragma unroll
      for (int j = 0; j < 4; ++j) {
        int row = wm * 32 + m2 * 16 + kgrp * 4 + j;
        float p0 = 0.f, p1 = 0.f;
#pragma unroll
        for (int n = 0; n < 4; ++n) {
          float r = fmaxf(acc[m2][n][j] + bev[n], 0.f);
          p0 = fmaf(r, wtv[0][n], p0);
          p1 = fmaf(r, wtv[1][n], p1);
        }
        outacc[m2][j][0] = fmaf(gates_lds[row][e],     p0, outacc[m2][j][0]);
        outacc[m2][j][1] = fmaf(gates_lds[row][8 + e], p1, outacc[m2][j][1]);
      }
    }
  }

  // ---- reduce over 16 col-lanes, across wn waves, then sigmoid out ----
#pragma unroll
  for (int m = 0; m < 2; ++m)
#pragma unroll
    for (int j = 0; j < 4; ++j)
#pragma unroll
      for (int t = 0; t < 2; ++t) {
        float v = outacc[m][j][t];
        v += __shfl_xor(v, 1);
        v += __shfl_xor(v, 2);
        v += __shfl_xor(v, 4);
        v += __shfl_xor(v, 8);
        outacc[m][j][t] = v;
      }
  if (row16 == 0) {
#pragma unroll
    for (int m = 0; m < 2; ++m)
#pragma unroll
      for (int j = 0; j < 4; ++j) {
        int lr = m * 16 + kgrp * 4 + j;
        red_lds[wave][lr][0] = outacc[m][j][0];
        red_lds[wave][lr][1] = outacc[m][j][1];
      }
  }
  __syncthreads();

  if (tid < 128) {
    int row = tid >> 1, t = tid & 1;
    int wmr = row >> 5, lr = row & 31;
    float s = red_lds[wmr * 4 + 0][lr][t] + red_lds[wmr * 4 + 1][lr][t]
            + red_lds[wmr * 4 + 2][lr][t] + red_lds[wmr * 4 + 3][lr][t];
    s += bt[t];
    s = fmaxf(s, 0.f);
    out[t * BS + b0 + row] = 1.f / (1.f + __expf(-s));
  }
}

extern "C" void kernel_launch(void* const* d_in, const int* in_sizes, int n_in,
                              void* d_out, int out_size, void* d_ws, size_t ws_size,
                              hipStream_t stream) {
  const float* xv = (const float*)d_in[0];
  const float* We = (const float*)d_in[1];
  const float* be = (const float*)d_in[2];
  const float* Wg = (const float*)d_in[3];
  const float* bg = (const float*)d_in[4];
  const float* Wt = (const float*)d_in[5];
  const float* bt = (const float*)d_in[6];
  float* out = (float*)d_out;

  unsigned char* ws = (unsigned char*)d_ws;
  unsigned short* WeT = (unsigned short*)(ws);               // 2 MiB
  unsigned short* WgT = (unsigned short*)(ws + (2u << 20));  // 16 KiB
  unsigned short* Asc = (unsigned short*)(ws + (4u << 20));  // 32 MiB (512 x 64KB)

  prep_weT<<<512, 256, 0, stream>>>(We, WeT);
  prep_wgT<<<16, 64, 0, stream>>>(Wg, WgT);
  mmoe_main<<<512, 512, 0, stream>>>(xv, WeT, WgT, be, bg, Wt, bt, Asc, out);
}

// Round 13
// 121.497 us; speedup vs baseline: 1.1597x; 1.1597x over previous
//
#include <hip/hip_runtime.h>

typedef __attribute__((ext_vector_type(8))) short short8;
typedef __attribute__((ext_vector_type(4))) float floatx4;
typedef __attribute__((ext_vector_type(4))) float f32x4;

#define BS   32768

__device__ __forceinline__ unsigned short f2bf(float f) {
  unsigned int u = __float_as_uint(f);
  u += 0x7fffu + ((u >> 16) & 1u);   // round-to-nearest-even
  return (unsigned short)(u >> 16);
}

// Transpose We [8][512][256] f32 -> WeT [8][256][512] bf16 (k-contiguous rows)
__global__ void prep_weT(const float* __restrict__ We, unsigned short* __restrict__ WeT) {
  int e  = blockIdx.x >> 6;
  int kc = blockIdx.x & 63;
  int h  = threadIdx.x;
  short8 pk;
#pragma unroll
  for (int j = 0; j < 8; ++j)
    pk[j] = (short)f2bf(We[e * 131072 + (kc * 8 + j) * 256 + h]);
  *reinterpret_cast<short8*>(&WeT[e * 131072 + h * 512 + kc * 8]) = pk;
}

// Wg [2][512][8] f32 -> WgT [16][512] bf16, row = t*8+e
__global__ void prep_wgT(const float* __restrict__ Wg, unsigned short* __restrict__ WgT) {
  int row = blockIdx.x;
  int t = row >> 3, e = row & 7;
  int lane = threadIdx.x;
  short8 pk;
#pragma unroll
  for (int j = 0; j < 8; ++j)
    pk[j] = (short)f2bf(Wg[t * 4096 + (lane * 8 + j) * 8 + e]);
  *reinterpret_cast<short8*>(&WgT[row * 512 + lane * 8]) = pk;
}

#define GLOAD16(SRC, DST) \
  __builtin_amdgcn_global_load_lds( \
      (const __attribute__((address_space(1))) unsigned int*)(SRC), \
      (__attribute__((address_space(3))) unsigned int*)(DST), 16, 0, 0)

// kernel2: convert xv -> Abf (bf16, pre-swizzled 32KB chunks [mt][kc][256r][64k])
// and compute gates -> gates_ws[16][32768] (col-major planes, col = t*8+e).
__global__ __launch_bounds__(256) void conv_gates(
    const float* __restrict__ xv, const unsigned short* __restrict__ WgT,
    const float* __restrict__ bg, unsigned short* __restrict__ Abf,
    float* __restrict__ gates_ws)
{
  __shared__ __attribute__((aligned(16))) unsigned char bufA[65536]; // 64r x 1024B, swizzled
  const int tid = threadIdx.x;
  const int b0  = blockIdx.x * 64;
  const int r8 = tid >> 3, kslot = tid & 7;
  const int mt = b0 >> 8;
  const int rc_base = b0 & 255;
  unsigned char* AbfB = reinterpret_cast<unsigned char*>(Abf);

#pragma unroll
  for (int pass = 0; pass < 2; ++pass) {
    int r = pass * 32 + r8;                 // local row 0..63
    int r_c = rc_base + r;                  // row within 256-row m-tile
    const float* xrow = xv + (size_t)(b0 + r) * 512;
    unsigned swz = (unsigned)((r & 7) << 4);
#pragma unroll
    for (int j = 0; j < 8; ++j) {           // j = k-chunk (64 k each)
      int o = j * 8 + kslot;                // k-octet index 0..63
      f32x4 v0 = *reinterpret_cast<const f32x4*>(xrow + o * 8);
      f32x4 v1 = *reinterpret_cast<const f32x4*>(xrow + o * 8 + 4);
      short8 pk;
      pk[0] = (short)f2bf(v0[0]); pk[1] = (short)f2bf(v0[1]);
      pk[2] = (short)f2bf(v0[2]); pk[3] = (short)f2bf(v0[3]);
      pk[4] = (short)f2bf(v1[0]); pk[5] = (short)f2bf(v1[1]);
      pk[6] = (short)f2bf(v1[2]); pk[7] = (short)f2bf(v1[3]);
      unsigned lb = ((unsigned)r << 10) + (((unsigned)(o * 16)) ^ swz);
      *reinterpret_cast<short8*>(&bufA[lb]) = pk;
      unsigned gb = (unsigned)((mt * 8 + j) * 32768) + (unsigned)(r_c * 128)
                  + (((unsigned)(kslot * 16)) ^ swz);
      *reinterpret_cast<short8*>(&AbfB[gb]) = pk;
    }
  }
  __syncthreads();

  const int wave = tid >> 6, lane = tid & 63;
  const int row16 = lane & 15, kgrp = lane >> 4;
  floatx4 gacc = {0.f, 0.f, 0.f, 0.f};
  const unsigned abase = ((unsigned)row16 << 10) + ((unsigned)kgrp << 4) + ((unsigned)wave << 14);
  const unsigned a_swz = (unsigned)((row16 & 7) << 4);
  const unsigned short* wg_lane = WgT + row16 * 512 + kgrp * 8;
#pragma unroll
  for (int ks = 0; ks < 16; ++ks) {
    short8 af = *reinterpret_cast<const short8*>(&bufA[(abase + (unsigned)(ks << 6)) ^ a_swz]);
    short8 bf = *reinterpret_cast<const short8*>(wg_lane + ks * 32);
    gacc = __builtin_amdgcn_mfma_f32_16x16x32_bf16(af, bf, gacc, 0, 0, 0);
  }
  float bgv = bg[row16];
#pragma unroll
  for (int j = 0; j < 4; ++j) {
    float v = gacc[j] + bgv;
    float mx = v;
    mx = fmaxf(mx, __shfl_xor(mx, 1));
    mx = fmaxf(mx, __shfl_xor(mx, 2));
    mx = fmaxf(mx, __shfl_xor(mx, 4));
    float p = __expf(v - mx);
    float s = p;
    s += __shfl_xor(s, 1);
    s += __shfl_xor(s, 2);
    s += __shfl_xor(s, 4);
    gates_ws[row16 * BS + b0 + wave * 16 + kgrp * 4 + j] = p / s;
  }
}

// main: grid 1024. v13: XCD-locality swizzle -- e = bid>>7, mt = bid&127, so all
// 8 expert-blocks of one mt satisfy bid === mt (mod 8) -> same XCD -> A-chunk
// stays L2-resident across experts/rounds. Unified kt-top staging (A+B together,
// vmcnt(8)): full-kt prefetch distance for both operands. Otherwise v11.
__global__ __launch_bounds__(512, 2) void mmoe_main(
    const unsigned short* __restrict__ Abf,   // [128 mt][8 kc][16384] elems, pre-swizzled
    const unsigned short* __restrict__ WeT,   // [8][256][512]
    const float* __restrict__ gates_ws,       // [16][32768]
    const float* __restrict__ be,             // [8][256]
    const float* __restrict__ Wt,             // [2][256]
    float* __restrict__ acc_ws)               // [2][32768]
{
  __shared__ __attribute__((aligned(16))) unsigned char smem[131072]; // A0|A1|B0|B1 (32KB each)
  __shared__ float red_lds[4][256][2];

  const int tid = threadIdx.x, wave = tid >> 6, lane = tid & 63;
  const int row16 = lane & 15, kgrp = lane >> 4;
  const int wm = wave >> 2, wn = wave & 3;
  const int bid = blockIdx.x;
  const int e = bid >> 7, mt = bid & 127;     // XCD-locality mapping

  const unsigned short* Asrc = Abf + (size_t)mt * 131072;
  const unsigned short* Bsrc = WeT + e * 131072;

  unsigned soffB[4];
#pragma unroll
  for (int i = 0; i < 4; ++i) {
    unsigned x = (unsigned)(i * 8192 + tid * 16);
    unsigned r = x >> 7;
    unsigned y = (x & 127u) ^ ((r & 7u) << 4);
    soffB[i] = r * 512u + (y >> 1);
  }
  const unsigned soffA0 = (unsigned)(tid * 8);   // linear byte-match copy (pre-swizzled src)

  unsigned char* Ab0 = smem;
  unsigned char* Ab1 = smem + 32768;
  unsigned char* Bb0 = smem + 65536;
  unsigned char* Bb1 = smem + 98304;

  // prologue: stage kt0 (no drain -- kt0's vmcnt handles it)
#pragma unroll
  for (int i = 0; i < 4; ++i)
    GLOAD16(Asrc + (i * 4096 + soffA0), Ab0 + (i * 8 + wave) * 1024);
#pragma unroll
  for (int i = 0; i < 4; ++i)
    GLOAD16(Bsrc + soffB[i], Bb0 + (i * 8 + wave) * 1024);

  floatx4 acc[8][4];
#pragma unroll
  for (int mf = 0; mf < 8; ++mf)
#pragma unroll
    for (int n = 0; n < 4; ++n) acc[mf][n] = (floatx4){0.f, 0.f, 0.f, 0.f};

  const unsigned swz  = (unsigned)((row16 & 7) << 4);
  const unsigned bcol = (unsigned)(wn * 64 + row16);
  const unsigned arow = (unsigned)(wm * 128 + row16);

#define RDA(AB, MF, KS) \
  (*reinterpret_cast<const short8*>( \
      &(AB)[(arow + (unsigned)((MF) * 16)) * 128 + (((unsigned)((KS) * 64 + kgrp * 16)) ^ swz)]))

#define MFMA4(ACC, AV, BV) \
  _Pragma("unroll") \
  for (int n = 0; n < 4; ++n) \
    ACC[n] = __builtin_amdgcn_mfma_f32_16x16x32_bf16(AV, BV[n], ACC[n], 0, 0, 0);

#pragma unroll
  for (int kt = 0; kt < 8; ++kt) {
    const unsigned char* ab = (kt & 1) ? Ab1 : Ab0;
    const unsigned char* bb = (kt & 1) ? Bb1 : Bb0;
    unsigned char* an = (kt & 1) ? Ab0 : Ab1;
    unsigned char* bn = (kt & 1) ? Bb0 : Bb1;
    const unsigned short* aNext = Asrc + (kt + 1) * 16384;
    const unsigned short* bNext = Bsrc + (kt + 1) * 64;

    // ---- kt top: stage A(kt+1)+B(kt+1) together; counted vmcnt(8) ----
    if (kt < 7) {
#pragma unroll
      for (int i = 0; i < 4; ++i)
        GLOAD16(aNext + (i * 4096 + soffA0), an + (i * 8 + wave) * 1024);
#pragma unroll
      for (int i = 0; i < 4; ++i)
        GLOAD16(bNext + soffB[i], bn + (i * 8 + wave) * 1024);
      asm volatile("s_waitcnt vmcnt(8)" ::: "memory");   // kt's 8 done; kt+1's 8 in flight
    } else {
      asm volatile("s_waitcnt vmcnt(0)" ::: "memory");   // final kt
    }
    __builtin_amdgcn_s_barrier();                        // all waves' kt data landed
    __builtin_amdgcn_sched_barrier(0);                   // no ds_read hoist above barrier

    short8 bf[2][4];
#pragma unroll
    for (int ks = 0; ks < 2; ++ks)
#pragma unroll
      for (int n = 0; n < 4; ++n)
        bf[ks][n] = *reinterpret_cast<const short8*>(
            &bb[(bcol + (unsigned)(n * 16)) * 128 + (((unsigned)(ks * 64 + kgrp * 16)) ^ swz)]);
    short8 a00 = RDA(ab, 0, 0), a01 = RDA(ab, 0, 1);
    short8 a10 = RDA(ab, 1, 0), a11 = RDA(ab, 1, 1);
    short8 b00 = RDA(ab, 2, 0), b01 = RDA(ab, 2, 1);   // mf2,3 read-ahead
    short8 b10 = RDA(ab, 3, 0), b11 = RDA(ab, 3, 1);
    asm volatile("s_waitcnt lgkmcnt(4)" ::: "memory");   // bf + mf0,1 ready; mf2,3 in flight
    __builtin_amdgcn_sched_barrier(0);
    __builtin_amdgcn_s_setprio(1);
    MFMA4(acc[0], a00, bf[0]); MFMA4(acc[0], a01, bf[1]);
    MFMA4(acc[1], a10, bf[0]); MFMA4(acc[1], a11, bf[1]);
    __builtin_amdgcn_s_setprio(0);

    // ---- read-ahead mf4,5; MFMA mf2,3 ----
    short8 c00 = RDA(ab, 4, 0), c01 = RDA(ab, 4, 1);
    short8 c10 = RDA(ab, 5, 0), c11 = RDA(ab, 5, 1);
    asm volatile("s_waitcnt lgkmcnt(4)" ::: "memory");   // mf2,3 ready; mf4,5 in flight
    __builtin_amdgcn_sched_barrier(0);
    __builtin_amdgcn_s_setprio(1);
    MFMA4(acc[2], b00, bf[0]); MFMA4(acc[2], b01, bf[1]);
    MFMA4(acc[3], b10, bf[0]); MFMA4(acc[3], b11, bf[1]);
    __builtin_amdgcn_s_setprio(0);

    // ---- read-ahead mf6,7; MFMA mf4,5 ----
    short8 d00 = RDA(ab, 6, 0), d01 = RDA(ab, 6, 1);
    short8 d10 = RDA(ab, 7, 0), d11 = RDA(ab, 7, 1);
    asm volatile("s_waitcnt lgkmcnt(4)" ::: "memory");   // mf4,5 ready; mf6,7 in flight
    __builtin_amdgcn_sched_barrier(0);
    __builtin_amdgcn_s_setprio(1);
    MFMA4(acc[4], c00, bf[0]); MFMA4(acc[4], c01, bf[1]);
    MFMA4(acc[5], c10, bf[0]); MFMA4(acc[5], c11, bf[1]);
    __builtin_amdgcn_s_setprio(0);

    // ---- MFMA mf6,7; end-of-kt barrier (buffer-swap fence) ----
    asm volatile("s_waitcnt lgkmcnt(0)" ::: "memory");
    __builtin_amdgcn_sched_barrier(0);
    __builtin_amdgcn_s_setprio(1);
    MFMA4(acc[6], d00, bf[0]); MFMA4(acc[6], d01, bf[1]);
    MFMA4(acc[7], d10, bf[0]); MFMA4(acc[7], d11, bf[1]);
    __builtin_amdgcn_s_setprio(0);
    __builtin_amdgcn_s_barrier();                        // all reads of kt's bufs done
    __builtin_amdgcn_sched_barrier(0);
  }
#undef RDA
#undef MFMA4

  // epilogue: bias+relu -> Wt-dot -> col reduce -> wn reduce -> gate -> atomicAdd
  float bev[4], wtv[2][4];
#pragma unroll
  for (int n = 0; n < 4; ++n) bev[n] = be[e * 256 + wn * 64 + n * 16 + row16];
#pragma unroll
  for (int t = 0; t < 2; ++t)
#pragma unroll
    for (int n = 0; n < 4; ++n) wtv[t][n] = Wt[t * 256 + wn * 64 + n * 16 + row16];

#pragma unroll
  for (int mf = 0; mf < 8; ++mf) {
#pragma unroll
    for (int j = 0; j < 4; ++j) {
      float p0 = 0.f, p1 = 0.f;
#pragma unroll
      for (int n = 0; n < 4; ++n) {
        float r = fmaxf(acc[mf][n][j] + bev[n], 0.f);
        p0 = fmaf(r, wtv[0][n], p0);
        p1 = fmaf(r, wtv[1][n], p1);
      }
      p0 += __shfl_xor(p0, 1); p1 += __shfl_xor(p1, 1);
      p0 += __shfl_xor(p0, 2); p1 += __shfl_xor(p1, 2);
      p0 += __shfl_xor(p0, 4); p1 += __shfl_xor(p1, 4);
      p0 += __shfl_xor(p0, 8); p1 += __shfl_xor(p1, 8);
      if (row16 == 0) {
        int rw = wm * 128 + mf * 16 + kgrp * 4 + j;
        red_lds[wn][rw][0] = p0;
        red_lds[wn][rw][1] = p1;
      }
    }
  }
  __syncthreads();

  {
    int row = tid >> 1, t = tid & 1;
    float s = red_lds[0][row][t] + red_lds[1][row][t]
            + red_lds[2][row][t] + red_lds[3][row][t];
    float g = gates_ws[(t * 8 + e) * BS + mt * 256 + row];
    atomicAdd(&acc_ws[t * BS + mt * 256 + row], s * g);
  }
}

__global__ void finalize(const float* __restrict__ acc_ws, const float* __restrict__ bt,
                         float* __restrict__ out) {
  int i = blockIdx.x * 256 + threadIdx.x;   // 65536
  int t = i >> 15;
  float s = fmaxf(acc_ws[i] + bt[t], 0.f);
  out[i] = 1.f / (1.f + __expf(-s));
}

extern "C" void kernel_launch(void* const* d_in, const int* in_sizes, int n_in,
                              void* d_out, int out_size, void* d_ws, size_t ws_size,
                              hipStream_t stream) {
  const float* xv = (const float*)d_in[0];
  const float* We = (const float*)d_in[1];
  const float* be = (const float*)d_in[2];
  const float* Wg = (const float*)d_in[3];
  const float* bg = (const float*)d_in[4];
  const float* Wt = (const float*)d_in[5];
  const float* bt = (const float*)d_in[6];
  float* out = (float*)d_out;

  unsigned char* ws = (unsigned char*)d_ws;
  unsigned short* WeT      = (unsigned short*)(ws);                     // 2 MiB
  unsigned short* WgT      = (unsigned short*)(ws + (2u << 20));        // 16 KiB
  unsigned short* Abf      = (unsigned short*)(ws + (4u << 20));        // 32 MiB
  float*          gates_ws = (float*)(ws + (36u << 20));                // 2 MiB
  float*          acc_ws   = (float*)(ws + (38u << 20));                // 256 KiB

  hipMemsetAsync(acc_ws, 0, 2 * BS * sizeof(float), stream);
  prep_weT<<<512, 256, 0, stream>>>(We, WeT);
  prep_wgT<<<16, 64, 0, stream>>>(Wg, WgT);
  conv_gates<<<512, 256, 0, stream>>>(xv, WgT, bg, Abf, gates_ws);
  mmoe_main<<<1024, 512, 0, stream>>>(Abf, WeT, gates_ws, be, Wt, acc_ws);
  finalize<<<256, 256, 0, stream>>>(acc_ws, bt, out);
}